// Round 2
// baseline (412.679 us; speedup 1.0000x reference)
//
#include <hip/hip_runtime.h>

// MHA forward: x(2,2048,2048) fp32, Wq/Wk/Wv/Wo (2048,2048) fp32 -> out fp32.
// R5: attention occupancy fix. QBLK 128->64, pairs (p,31-p) -> 17 kt-iters
//     for every pair, grid 512 = 2 blocks/CU = 2 waves/SIMD (was 1).
//     P-store row slot XOR (r ^ ((r>>2)&2)) -> P write/read 2-way (free)
//     instead of 4-way bank conflict. setprio(1) around MFMA clusters.
//     Half-tile MFMA skip on even-qt diagonal. Defer-max rescale (THR=8).
//     GEMMs (R4 counted-vmcnt 3-ring pipeline) unchanged.

#define SEQ 2048
#define DMODEL 2048
#define NH 16
#define HD 128

typedef __attribute__((ext_vector_type(8))) short bf16x8;  // 8 bf16 = 4 VGPRs
typedef __attribute__((ext_vector_type(4))) float f32x4;

__device__ __forceinline__ unsigned short f2bf(float f) {  // RNE fp32->bf16
  unsigned int u = __float_as_uint(f);
  u += 0x7fffu + ((u >> 16) & 1u);
  return (unsigned short)(u >> 16);
}

__device__ __forceinline__ void g2l16(const void* g, void* l) {
  __builtin_amdgcn_global_load_lds((const __attribute__((address_space(1))) void*)g,
                                   (__attribute__((address_space(3))) void*)l,
                                   16, 0, 0);
}

__device__ __forceinline__ f32x4 mfma16(bf16x8 a, bf16x8 b, f32x4 c) {
  return __builtin_amdgcn_mfma_f32_16x16x32_bf16(a, b, c, 0, 0, 0);
}

template <int CTRL>
__device__ __forceinline__ float dpp_ror(float v) {
  return __int_as_float(__builtin_amdgcn_mov_dpp(__float_as_int(v), CTRL, 0xf, 0xf, false));
}
__device__ __forceinline__ float red_max16(float v) {
  v = fmaxf(v, dpp_ror<0x128>(v));
  v = fmaxf(v, dpp_ror<0x124>(v));
  v = fmaxf(v, dpp_ror<0x122>(v));
  v = fmaxf(v, dpp_ror<0x121>(v));
  return v;
}
__device__ __forceinline__ float red_sum16(float v) {
  v += dpp_ror<0x128>(v);
  v += dpp_ror<0x124>(v);
  v += dpp_ror<0x122>(v);
  v += dpp_ror<0x121>(v);
  return v;
}

// one launch: converts x + all four weights to bf16, permutes Wq/Wk rows
// within-head (RoPE pairs -> adjacent 16-col fragments), fills rope table.
__global__ __launch_bounds__(256) void cvt_all(const float* __restrict__ x,
                                               const float* __restrict__ wq,
                                               const float* __restrict__ wk,
                                               const float* __restrict__ wv,
                                               const float* __restrict__ wo,
                                               unsigned short* __restrict__ dst0,
                                               float2* __restrict__ rtab) {
  const int b = blockIdx.x;
  if (b >= 24576) {  // rope cos/sin table: 2048 x 64
    const int idx = (b - 24576) * 256 + threadIdx.x;  // [0, 131072)
    const int s = idx >> 6, d = idx & 63;
    float sn, cs;
    sincosf((float)s * exp2f(-0.20762050593046f * (float)d), &sn, &cs);
    rtab[idx] = make_float2(cs, sn);
    return;
  }
  const float* src;
  unsigned short* dst;
  int idx, r = -1;
  if (b < 8192) {  // x: 2097152 float4's
    src = x; dst = dst0; idx = b * 256 + threadIdx.x;
  } else {
    r = (b - 8192) >> 12;  // 4096 blocks per weight
    src = (r == 0) ? wq : (r == 1) ? wk : (r == 2) ? wv : wo;
    dst = dst0 + (size_t)2 * SEQ * DMODEL + (size_t)r * DMODEL * DMODEL;
    idx = ((b - 8192) & 4095) * 256 + threadIdx.x;
  }
  const float4 v = ((const float4*)src)[idx];
  ushort4 o;
  o.x = f2bf(v.x); o.y = f2bf(v.y); o.z = f2bf(v.z); o.w = f2bf(v.w);
  int widx = idx;
  if (r == 0 || r == 1) {  // permute Wq/Wk output-feature rows within head
    const int row = idx >> 9, col = idx & 511;
    const int o_ = row & 127;
    const int e = (((o_ >> 4) & 3) << 5) | (((o_ >> 6) & 1) << 4) | (o_ & 15);
    widx = (((row & ~127) | e) << 9) | col;
  }
  ((ushort4*)dst)[widx] = o;
}

// ---------------------------------------------------------------------------
// Pipelined GEMM core: C[m,n] = sum_k A[m,k]*B[n,k].
// BM=256, BN=128, BK=64. 512 threads = 8 waves (4M x 2N), wave tile 64x64.
// 3-deep LDS ring (144 KB), counted vmcnt(6) + raw s_barrier per K-tile.
// MODE 0: fused QKV (N=6144); MODE 1: attn_out @ Wo^T, fp32 store.
// ---------------------------------------------------------------------------
template <int MODE>
__global__ __launch_bounds__(512, 2) void gemm_pipe(
    const unsigned short* __restrict__ A,
    const unsigned short* __restrict__ B,
    unsigned short* __restrict__ obf,   // MODE0: qb (kb=+NX, vb=+2NX)
    float* __restrict__ of32,           // MODE1: output
    const float2* __restrict__ rtab) {
  __shared__ unsigned short lds[3 * 24576];  // 147456 B
  const int nb = blockIdx.x, mb = blockIdx.y;
  const int M0 = mb * 256;
  const int t = threadIdx.x;
  const int w = t >> 6, lane = t & 63, l15 = lane & 15, quad = lane >> 4;
  const int g = lane >> 3, j = lane & 7;
  const int wm = w >> 1, wn = w & 1;

  const unsigned short* Abase = A + (size_t)M0 * DMODEL;
  const unsigned short* Bbase = B + (size_t)nb * 128 * DMODEL;

  f32x4 acc[4][4] = {};

  auto stage = [&](int buf, int k0, int i0) {
#pragma unroll
    for (int i = 0; i < 3; ++i) {
      const int u = w * 6 + i0 + i;
      if (u < 32) {
        const int row = u * 8 + g;
        g2l16(Abase + (size_t)row * DMODEL + k0 + ((j ^ g) << 3),
              &lds[buf * 24576 + u * 512]);
      } else {
        const int row = (u - 32) * 8 + g;
        g2l16(Bbase + (size_t)row * DMODEL + k0 + ((j ^ g) << 3),
              &lds[buf * 24576 + 16384 + (u - 32) * 512]);
      }
    }
  };

  auto comp = [&](int buf, int kc) {
    const int c = kc * 4 + quad;
    const unsigned short* As_ = &lds[buf * 24576];
    const unsigned short* Bs_ = &lds[buf * 24576 + 16384];
    bf16x8 af[4], bf[4];
#pragma unroll
    for (int mt = 0; mt < 4; ++mt) {
      const int m = wm * 64 + mt * 16 + l15;
      af[mt] = *(const bf16x8*)&As_[m * 64 + ((c ^ (m & 7)) << 3)];
    }
#pragma unroll
    for (int nt = 0; nt < 4; ++nt) {
      const int n = wn * 64 + nt * 16 + l15;
      bf[nt] = *(const bf16x8*)&Bs_[n * 64 + ((c ^ (n & 7)) << 3)];
    }
#pragma unroll
    for (int nt = 0; nt < 4; ++nt)
#pragma unroll
      for (int mt = 0; mt < 4; ++mt)
        acc[mt][nt] = mfma16(af[mt], bf[nt], acc[mt][nt]);
  };

  stage(0, 0, 0);
  stage(0, 0, 3);
  stage(1, 64, 0);
  stage(1, 64, 3);
  asm volatile("s_waitcnt vmcnt(6)\n\ts_barrier" ::: "memory");

  int buf = 0, b2 = 2;
  for (int tt = 0; tt < 32; ++tt) {
    const int k0 = tt * 64;
    if (tt < 30) stage(b2, k0 + 128, 0);
    comp(buf, 0);
    if (tt < 30) stage(b2, k0 + 128, 3);
    comp(buf, 1);
    if (tt < 30) {
      asm volatile("s_waitcnt vmcnt(6)\n\ts_barrier" ::: "memory");
    } else if (tt == 30) {
      asm volatile("s_waitcnt vmcnt(0)\n\ts_barrier" ::: "memory");
    }
    buf = (buf == 2) ? 0 : buf + 1;
    b2 = (b2 == 2) ? 0 : b2 + 1;
  }

  // Epilogue. C/D layout: col = l15 (N side), row = quad*4 + reg (M side).
  if (MODE == 0) {
    const size_t NX = (size_t)2 * SEQ * DMODEL;
    const int z = nb >> 4;  // 0:Q 1:K 2:V (BN=128 == one head)
    const int h = nb & 15;
    if (z < 2) {
      const float qscale = (z == 0) ? 0.1275174356f : 1.0f;
      unsigned short* O = obf + (size_t)z * NX;
#pragma unroll
      for (int mt = 0; mt < 4; ++mt)
#pragma unroll
        for (int reg = 0; reg < 4; ++reg) {
          const int m = M0 + wm * 64 + mt * 16 + quad * 4 + reg;
          const int bb = m >> 11, s = m & 2047;
          unsigned short* ob = O + ((size_t)(bb * NH + h) * SEQ + s) * HD;
#pragma unroll
          for (int p = 0; p < 2; ++p) {
            const int q = wn * 2 + p;
            const float2 cs = rtab[s * 64 + q * 16 + l15];
            const float x1 = acc[mt][2 * p][reg], x2 = acc[mt][2 * p + 1][reg];
            ob[wn * 64 + (2 * p) * 16 + l15] = f2bf((x1 * cs.x - x2 * cs.y) * qscale);
            ob[wn * 64 + (2 * p + 1) * 16 + l15] = f2bf((x2 * cs.x + x1 * cs.y) * qscale);
          }
        }
    } else {
      unsigned short* Vb = obf + 2 * NX + (size_t)h * HD * SEQ;
#pragma unroll
      for (int mt = 0; mt < 4; ++mt)
#pragma unroll
        for (int reg = 0; reg < 4; ++reg) {
          const int m = M0 + wm * 64 + mt * 16 + quad * 4 + reg;
          const int bb = m >> 11, s = m & 2047;
          unsigned short* ob = Vb + (size_t)bb * NH * HD * SEQ;
#pragma unroll
          for (int nt = 0; nt < 4; ++nt)
            ob[(size_t)(wn * 64 + nt * 16 + l15) * SEQ + s] = f2bf(acc[mt][nt][reg]);
        }
    }
  } else {
#pragma unroll
    for (int mt = 0; mt < 4; ++mt)
#pragma unroll
      for (int reg = 0; reg < 4; ++reg) {
        const int m = M0 + wm * 64 + mt * 16 + quad * 4 + reg;
#pragma unroll
        for (int nt = 0; nt < 4; ++nt)
          of32[(size_t)m * DMODEL + nb * 128 + wn * 64 + nt * 16 + l15] =
              acc[mt][nt][reg];
      }
  }
}

// ---------------------------------------------------------------------------
// Flash attention, causal. QBLK=64, KVBLK=128. Block = one (b,h) x pair of
// q-tiles (p, 31-p): every pair = exactly 17 kt-iterations. Grid 512 =
// 2 blocks/CU (64 KB LDS each) = 2 waves/SIMD. 4 waves, 16 q-rows/wave.
// P stored at row slot r ^ ((r>>2)&2) -> write/read both 2-way (free).
// bh = gid&31 keeps all 16 pair-blocks of one bh on XCD bh%8 (4MB KV = L2).
// ---------------------------------------------------------------------------
__global__ __launch_bounds__(256) void attn_kernel(const unsigned short* __restrict__ Q,
                                                   const unsigned short* __restrict__ K,
                                                   const unsigned short* __restrict__ Vt,
                                                   unsigned short* __restrict__ Oa) {
  __shared__ unsigned short Ks[256 * 64];  // 32 KB (reused as P after QK^T)
  __shared__ unsigned short Vs[256 * 64];  // 32 KB
  const int gid = blockIdx.x;
  const int bh = gid & 31;
  const int pr = gid >> 5;  // pair index 0..15
  const unsigned short* Qb = Q + (size_t)bh * SEQ * HD;
  const unsigned short* Kb = K + (size_t)bh * SEQ * HD;
  const unsigned short* Vb = Vt + (size_t)bh * HD * SEQ;
  const int t = threadIdx.x;
  const int w = t >> 6, lane = t & 63, l15 = lane & 15, quad = lane >> 4;
  const int g = lane >> 3, j = lane & 7;
  const int b = bh >> 4, h = bh & 15;
  const int r2r = l15 ^ ((l15 >> 2) & 2);  // P-row de-swizzle for read

  for (int half = 0; half < 2; ++half) {
    const int qt = half ? 31 - pr : pr;  // q-tile of 64 rows
    const int ktmax = (qt * 64 + 63) >> 7;

    // Q fragments: A-layout row = l15, k(hd) = ch*32 + quad*8
    bf16x8 qf[4];
#pragma unroll
    for (int ch = 0; ch < 4; ++ch)
      qf[ch] = *(const bf16x8*)(Qb + (size_t)(qt * 64 + w * 16 + l15) * HD +
                                ch * 32 + quad * 8);

    f32x4 o[8] = {};
    float mrow[4], lrow[4];
#pragma unroll
    for (int reg = 0; reg < 4; ++reg) { mrow[reg] = -1e30f; lrow[reg] = 0.f; }

    for (int kt = 0; kt <= ktmax; ++kt) {
      __syncthreads();
#pragma unroll
      for (int r = 0; r < 16; ++r) {  // 64 units: 32 K + 32 V
        const int u = r * 4 + w;
        if (u < 32) {
          const int vrow = u * 8 + g, key = vrow >> 1;
          const int ck = j ^ (key & 7);
          g2l16(Kb + (size_t)(kt * 128 + key) * HD + (vrow & 1) * 64 + ck * 8, &Ks[u * 512]);
        } else {
          const int u2 = u - 32;
          const int vrow = u2 * 8 + g, d = vrow >> 1;
          const int cv = j ^ (d & 7);
          g2l16(Vb + (size_t)d * SEQ + kt * 128 + (vrow & 1) * 64 + cv * 8, &Vs[u2 * 512]);
        }
      }
      __syncthreads();

      // S = Q K^T (Q pre-scaled by log2e/sqrt(hd)). On the diagonal tile of
      // even qt, keys [64..128) are fully masked -> skip those 16 MFMAs.
      const bool halftile = (kt == ktmax) && !(qt & 1);
      f32x4 s[8] = {};
      __builtin_amdgcn_s_setprio(1);
#pragma unroll
      for (int ch = 0; ch < 4; ++ch) {
        const int hh = ch >> 1, c = (ch & 1) * 4 + quad;
#pragma unroll
        for (int nt = 0; nt < 4; ++nt) {
          const int n = nt * 16 + l15;
          const bf16x8 bv = *(const bf16x8*)&Ks[(n * 2 + hh) * 64 + ((c ^ (n & 7)) << 3)];
          s[nt] = mfma16(qf[ch], bv, s[nt]);
        }
      }
      if (!halftile) {
#pragma unroll
        for (int ch = 0; ch < 4; ++ch) {
          const int hh = ch >> 1, c = (ch & 1) * 4 + quad;
#pragma unroll
          for (int nt = 4; nt < 8; ++nt) {
            const int n = nt * 16 + l15;
            const bf16x8 bv = *(const bf16x8*)&Ks[(n * 2 + hh) * 64 + ((c ^ (n & 7)) << 3)];
            s[nt] = mfma16(qf[ch], bv, s[nt]);
          }
        }
      }
      __builtin_amdgcn_s_setprio(0);

      if (kt == ktmax) {  // causal mask on diagonal tile
#pragma unroll
        for (int nt = 0; nt < 8; ++nt)
#pragma unroll
          for (int reg = 0; reg < 4; ++reg) {
            const int rr = qt * 64 + w * 16 + quad * 4 + reg;
            const int cc = kt * 128 + nt * 16 + l15;
            if (cc > rr) s[nt][reg] = -1e30f;
          }
      }

      // online softmax in log2 domain, defer-max rescale (THR=8)
#pragma unroll
      for (int reg = 0; reg < 4; ++reg) {
        float vmax = s[0][reg];
#pragma unroll
        for (int nt = 1; nt < 8; ++nt) vmax = fmaxf(vmax, s[nt][reg]);
        vmax = red_max16(vmax);
        const float mo = mrow[reg];
        float mn = mo;
        if (!__all(vmax <= mo + 8.0f)) {  // wave-uniform branch
          mn = fmaxf(mo, vmax);
          const float alpha = exp2f(mo - mn);
          mrow[reg] = mn;
          lrow[reg] *= alpha;
#pragma unroll
          for (int nt = 0; nt < 8; ++nt) o[nt][reg] *= alpha;
        }
        float rs = 0.f;
#pragma unroll
        for (int nt = 0; nt < 8; ++nt) {
          const float p_ = exp2f(s[nt][reg] - mn);
          s[nt][reg] = p_;
          rs += p_;
        }
        rs = red_sum16(rs);
        lrow[reg] += rs;
      }

      __syncthreads();  // all waves done reading Ks before P overwrites it

      // P write: wave-private 16 planes x 16 rows x 8, row slot XOR'd so the
      // 64-lane b16 scatter is 2 lanes/bank (same dword) instead of 4-way.
      unsigned short* Pw = &Ks[w * 2048];
#pragma unroll
      for (int nt = 0; nt < 8; ++nt)
#pragma unroll
        for (int reg = 0; reg < 4; ++reg) {
          const int r2 = quad * 4 + (reg ^ (quad & 2));
          const int key = nt * 16 + l15;
          Pw[(key >> 3) * 128 + r2 * 8 + (key & 7)] = f2bf(s[nt][reg]);
        }

      // O += P V
      __builtin_amdgcn_s_setprio(1);
#pragma unroll
      for (int ch = 0; ch < 4; ++ch) {
        const int kh = ch >> 1, c = (ch & 1) * 4 + quad;
        const bf16x8 pa = *(const bf16x8*)&Pw[(ch * 4 + quad) * 128 + r2r * 8];
#pragma unroll
        for (int nt = 0; nt < 8; ++nt) {
          const int d = nt * 16 + l15;
          const bf16x8 vv = *(const bf16x8*)&Vs[(d * 2 + kh) * 64 + ((c ^ (d & 7)) << 3)];
          o[nt] = mfma16(pa, vv, o[nt]);
        }
      }
      __builtin_amdgcn_s_setprio(0);
    }

    // epilogue: normalize and store attn output as (B*S, D) bf16
#pragma unroll
    for (int reg = 0; reg < 4; ++reg) {
      const int sq = qt * 64 + w * 16 + quad * 4 + reg;
      const float inv_l = 1.0f / lrow[reg];
      unsigned short* ob = Oa + (size_t)(b * SEQ + sq) * DMODEL + h * HD;
#pragma unroll
      for (int nt = 0; nt < 8; ++nt) ob[nt * 16 + l15] = f2bf(o[nt][reg] * inv_l);
    }
  }
}

extern "C" void kernel_launch(void* const* d_in, const int* in_sizes, int n_in,
                              void* d_out, int out_size, void* d_ws, size_t ws_size,
                              hipStream_t stream) {
  const float* x = (const float*)d_in[0];
  const float* Wq = (const float*)d_in[1];
  const float* Wk = (const float*)d_in[2];
  const float* Wv = (const float*)d_in[3];
  const float* Wo = (const float*)d_in[4];
  float* out = (float*)d_out;

  const size_t NX = (size_t)2 * SEQ * DMODEL;
  const size_t NW = (size_t)DMODEL * DMODEL;
  unsigned short* ws = (unsigned short*)d_ws;
  unsigned short* xb = ws;
  unsigned short* wqb = xb + NX;   // wq/wk/wv contiguous -> fused N=6144 B operand
  unsigned short* wkb = wqb + NW;
  unsigned short* wvb = wkb + NW;
  unsigned short* wob = wvb + NW;
  unsigned short* qb = wob + NW;  // (B,H,S,hd) permuted-hd, rope'd, *log2e/sqrt(hd)
  unsigned short* kb = qb + NX;   // (B,H,S,hd) permuted-hd, rope'd
  unsigned short* vb = kb + NX;   // (B,H,hd,S)
  unsigned short* ab = vb + NX;   // (B*S, D)
  float2* rtab = (float2*)(ab + NX);  // 2048 x 64 cos/sin (1 MB)

  cvt_all<<<25088, 256, 0, stream>>>(x, Wq, Wk, Wv, Wo, ws, rtab);
  gemm_pipe<0><<<dim3(48, 16), 512, 0, stream>>>(xb, wqb, qb, nullptr, rtab);
  attn_kernel<<<512, 256, 0, stream>>>(qb, kb, vb, ab);
  gemm_pipe<1><<<dim3(16, 16), 512, 0, stream>>>(ab, wob, nullptr, out, nullptr);
}

// Round 3
// 377.143 us; speedup vs baseline: 1.0942x; 1.0942x over previous
//
#include <hip/hip_runtime.h>

// MHA forward: x(2,2048,2048) fp32, Wq/Wk/Wv/Wo (2048,2048) fp32 -> out fp32.
// R6: attention pipelined like the GEMM. KVBLK=64 double-buffered K/V staged
//     with counted-latency schedule (stage kt+1 at top of iter kt, single
//     vmcnt(0)+s_barrier at iter end -> load latency hidden under compute).
//     Dedicated wave-private P buffer (no barrier for P round-trip).
//     Barriers/iter: 3 -> 1. LDS 72KB -> 2 blocks/CU. Diagonal tile skips
//     nt>w (fully masked). GEMMs (R4 counted-vmcnt 3-ring) unchanged.

#define SEQ 2048
#define DMODEL 2048
#define NH 16
#define HD 128

typedef __attribute__((ext_vector_type(8))) short bf16x8;  // 8 bf16 = 4 VGPRs
typedef __attribute__((ext_vector_type(4))) float f32x4;

__device__ __forceinline__ unsigned short f2bf(float f) {  // RNE fp32->bf16
  unsigned int u = __float_as_uint(f);
  u += 0x7fffu + ((u >> 16) & 1u);
  return (unsigned short)(u >> 16);
}

__device__ __forceinline__ void g2l16(const void* g, void* l) {
  __builtin_amdgcn_global_load_lds((const __attribute__((address_space(1))) void*)g,
                                   (__attribute__((address_space(3))) void*)l,
                                   16, 0, 0);
}

__device__ __forceinline__ f32x4 mfma16(bf16x8 a, bf16x8 b, f32x4 c) {
  return __builtin_amdgcn_mfma_f32_16x16x32_bf16(a, b, c, 0, 0, 0);
}

template <int CTRL>
__device__ __forceinline__ float dpp_ror(float v) {
  return __int_as_float(__builtin_amdgcn_mov_dpp(__float_as_int(v), CTRL, 0xf, 0xf, false));
}
__device__ __forceinline__ float red_max16(float v) {
  v = fmaxf(v, dpp_ror<0x128>(v));
  v = fmaxf(v, dpp_ror<0x124>(v));
  v = fmaxf(v, dpp_ror<0x122>(v));
  v = fmaxf(v, dpp_ror<0x121>(v));
  return v;
}
__device__ __forceinline__ float red_sum16(float v) {
  v += dpp_ror<0x128>(v);
  v += dpp_ror<0x124>(v);
  v += dpp_ror<0x122>(v);
  v += dpp_ror<0x121>(v);
  return v;
}

// one launch: converts x + all four weights to bf16, permutes Wq/Wk rows
// within-head (RoPE pairs -> adjacent 16-col fragments), fills rope table.
__global__ __launch_bounds__(256) void cvt_all(const float* __restrict__ x,
                                               const float* __restrict__ wq,
                                               const float* __restrict__ wk,
                                               const float* __restrict__ wv,
                                               const float* __restrict__ wo,
                                               unsigned short* __restrict__ dst0,
                                               float2* __restrict__ rtab) {
  const int b = blockIdx.x;
  if (b >= 24576) {  // rope cos/sin table: 2048 x 64
    const int idx = (b - 24576) * 256 + threadIdx.x;  // [0, 131072)
    const int s = idx >> 6, d = idx & 63;
    float sn, cs;
    sincosf((float)s * exp2f(-0.20762050593046f * (float)d), &sn, &cs);
    rtab[idx] = make_float2(cs, sn);
    return;
  }
  const float* src;
  unsigned short* dst;
  int idx, r = -1;
  if (b < 8192) {  // x: 2097152 float4's
    src = x; dst = dst0; idx = b * 256 + threadIdx.x;
  } else {
    r = (b - 8192) >> 12;  // 4096 blocks per weight
    src = (r == 0) ? wq : (r == 1) ? wk : (r == 2) ? wv : wo;
    dst = dst0 + (size_t)2 * SEQ * DMODEL + (size_t)r * DMODEL * DMODEL;
    idx = ((b - 8192) & 4095) * 256 + threadIdx.x;
  }
  const float4 v = ((const float4*)src)[idx];
  ushort4 o;
  o.x = f2bf(v.x); o.y = f2bf(v.y); o.z = f2bf(v.z); o.w = f2bf(v.w);
  int widx = idx;
  if (r == 0 || r == 1) {  // permute Wq/Wk output-feature rows within head
    const int row = idx >> 9, col = idx & 511;
    const int o_ = row & 127;
    const int e = (((o_ >> 4) & 3) << 5) | (((o_ >> 6) & 1) << 4) | (o_ & 15);
    widx = (((row & ~127) | e) << 9) | col;
  }
  ((ushort4*)dst)[widx] = o;
}

// ---------------------------------------------------------------------------
// Pipelined GEMM core: C[m,n] = sum_k A[m,k]*B[n,k].
// BM=256, BN=128, BK=64. 512 threads = 8 waves (4M x 2N), wave tile 64x64.
// 3-deep LDS ring (144 KB), counted vmcnt(6) + raw s_barrier per K-tile.
// MODE 0: fused QKV (N=6144); MODE 1: attn_out @ Wo^T, fp32 store.
// ---------------------------------------------------------------------------
template <int MODE>
__global__ __launch_bounds__(512, 2) void gemm_pipe(
    const unsigned short* __restrict__ A,
    const unsigned short* __restrict__ B,
    unsigned short* __restrict__ obf,   // MODE0: qb (kb=+NX, vb=+2NX)
    float* __restrict__ of32,           // MODE1: output
    const float2* __restrict__ rtab) {
  __shared__ unsigned short lds[3 * 24576];  // 147456 B
  const int nb = blockIdx.x, mb = blockIdx.y;
  const int M0 = mb * 256;
  const int t = threadIdx.x;
  const int w = t >> 6, lane = t & 63, l15 = lane & 15, quad = lane >> 4;
  const int g = lane >> 3, j = lane & 7;
  const int wm = w >> 1, wn = w & 1;

  const unsigned short* Abase = A + (size_t)M0 * DMODEL;
  const unsigned short* Bbase = B + (size_t)nb * 128 * DMODEL;

  f32x4 acc[4][4] = {};

  auto stage = [&](int buf, int k0, int i0) {
#pragma unroll
    for (int i = 0; i < 3; ++i) {
      const int u = w * 6 + i0 + i;
      if (u < 32) {
        const int row = u * 8 + g;
        g2l16(Abase + (size_t)row * DMODEL + k0 + ((j ^ g) << 3),
              &lds[buf * 24576 + u * 512]);
      } else {
        const int row = (u - 32) * 8 + g;
        g2l16(Bbase + (size_t)row * DMODEL + k0 + ((j ^ g) << 3),
              &lds[buf * 24576 + 16384 + (u - 32) * 512]);
      }
    }
  };

  auto comp = [&](int buf, int kc) {
    const int c = kc * 4 + quad;
    const unsigned short* As_ = &lds[buf * 24576];
    const unsigned short* Bs_ = &lds[buf * 24576 + 16384];
    bf16x8 af[4], bf[4];
#pragma unroll
    for (int mt = 0; mt < 4; ++mt) {
      const int m = wm * 64 + mt * 16 + l15;
      af[mt] = *(const bf16x8*)&As_[m * 64 + ((c ^ (m & 7)) << 3)];
    }
#pragma unroll
    for (int nt = 0; nt < 4; ++nt) {
      const int n = wn * 64 + nt * 16 + l15;
      bf[nt] = *(const bf16x8*)&Bs_[n * 64 + ((c ^ (n & 7)) << 3)];
    }
#pragma unroll
    for (int nt = 0; nt < 4; ++nt)
#pragma unroll
      for (int mt = 0; mt < 4; ++mt)
        acc[mt][nt] = mfma16(af[mt], bf[nt], acc[mt][nt]);
  };

  stage(0, 0, 0);
  stage(0, 0, 3);
  stage(1, 64, 0);
  stage(1, 64, 3);
  asm volatile("s_waitcnt vmcnt(6)\n\ts_barrier" ::: "memory");

  int buf = 0, b2 = 2;
  for (int tt = 0; tt < 32; ++tt) {
    const int k0 = tt * 64;
    if (tt < 30) stage(b2, k0 + 128, 0);
    comp(buf, 0);
    if (tt < 30) stage(b2, k0 + 128, 3);
    comp(buf, 1);
    if (tt < 30) {
      asm volatile("s_waitcnt vmcnt(6)\n\ts_barrier" ::: "memory");
    } else if (tt == 30) {
      asm volatile("s_waitcnt vmcnt(0)\n\ts_barrier" ::: "memory");
    }
    buf = (buf == 2) ? 0 : buf + 1;
    b2 = (b2 == 2) ? 0 : b2 + 1;
  }

  // Epilogue. C/D layout: col = l15 (N side), row = quad*4 + reg (M side).
  if (MODE == 0) {
    const size_t NX = (size_t)2 * SEQ * DMODEL;
    const int z = nb >> 4;  // 0:Q 1:K 2:V (BN=128 == one head)
    const int h = nb & 15;
    if (z < 2) {
      const float qscale = (z == 0) ? 0.1275174356f : 1.0f;
      unsigned short* O = obf + (size_t)z * NX;
#pragma unroll
      for (int mt = 0; mt < 4; ++mt)
#pragma unroll
        for (int reg = 0; reg < 4; ++reg) {
          const int m = M0 + wm * 64 + mt * 16 + quad * 4 + reg;
          const int bb = m >> 11, s = m & 2047;
          unsigned short* ob = O + ((size_t)(bb * NH + h) * SEQ + s) * HD;
#pragma unroll
          for (int p = 0; p < 2; ++p) {
            const int q = wn * 2 + p;
            const float2 cs = rtab[s * 64 + q * 16 + l15];
            const float x1 = acc[mt][2 * p][reg], x2 = acc[mt][2 * p + 1][reg];
            ob[wn * 64 + (2 * p) * 16 + l15] = f2bf((x1 * cs.x - x2 * cs.y) * qscale);
            ob[wn * 64 + (2 * p + 1) * 16 + l15] = f2bf((x2 * cs.x + x1 * cs.y) * qscale);
          }
        }
    } else {
      unsigned short* Vb = obf + 2 * NX + (size_t)h * HD * SEQ;
#pragma unroll
      for (int mt = 0; mt < 4; ++mt)
#pragma unroll
        for (int reg = 0; reg < 4; ++reg) {
          const int m = M0 + wm * 64 + mt * 16 + quad * 4 + reg;
          const int bb = m >> 11, s = m & 2047;
          unsigned short* ob = Vb + (size_t)bb * NH * HD * SEQ;
#pragma unroll
          for (int nt = 0; nt < 4; ++nt)
            ob[(size_t)(wn * 64 + nt * 16 + l15) * SEQ + s] = f2bf(acc[mt][nt][reg]);
        }
    }
  } else {
#pragma unroll
    for (int mt = 0; mt < 4; ++mt)
#pragma unroll
      for (int reg = 0; reg < 4; ++reg) {
        const int m = M0 + wm * 64 + mt * 16 + quad * 4 + reg;
#pragma unroll
        for (int nt = 0; nt < 4; ++nt)
          of32[(size_t)m * DMODEL + nb * 128 + wn * 64 + nt * 16 + l15] =
              acc[mt][nt][reg];
      }
  }
}

// ---------------------------------------------------------------------------
// Flash attention, causal. QBLK=64, KVBLK=64, double-buffered K/V.
// Block = one (b,h) x q-tile pair (p, 31-p): (p+1)+(32-p) = 33 kt-iters for
// every block (perfect balance). Grid 512 = 2 blocks/CU (72 KB LDS each).
// Per iter: stage(kt+1 -> buf^1) ; QK^T(buf) ; softmax ; P->wave-private LDS
// (no barrier) ; PV(buf) ; vmcnt(0)+s_barrier (loads issued a full iteration
// earlier -> latency hidden). One barrier per iteration, never a cold drain.
// K layout: [key][16 chunks], chunk slot = c ^ (key&7). V (transposed src):
// [d][8 chunks], slot = c ^ (d&7). Both conflict-free on ds_read_b128.
// ---------------------------------------------------------------------------
__global__ __launch_bounds__(256) void attn_kernel(const unsigned short* __restrict__ Q,
                                                   const unsigned short* __restrict__ K,
                                                   const unsigned short* __restrict__ Vt,
                                                   unsigned short* __restrict__ Oa) {
  __shared__ unsigned short Ks[2][64 * 128];  // 2 x 16 KB
  __shared__ unsigned short Vs[2][128 * 64];  // 2 x 16 KB
  __shared__ unsigned short Ps[4][1024];      // 4 x 2 KB wave-private P
  const int gid = blockIdx.x;
  const int bh = gid & 31;  // all 16 pair-blocks of one bh on XCD bh%8
  const int pr = gid >> 5;  // pair index 0..15
  const unsigned short* Qb = Q + (size_t)bh * SEQ * HD;
  const unsigned short* Kb = K + (size_t)bh * SEQ * HD;
  const unsigned short* Vb = Vt + (size_t)bh * HD * SEQ;
  const int t = threadIdx.x;
  const int w = t >> 6, lane = t & 63, l15 = lane & 15, quad = lane >> 4;
  const int l7 = lane & 7;
  const int b = bh >> 4, h = bh & 15;
  const int uA = w * 64 + lane;  // staging unit base (i*256 added per instr)

  // stage K/V tile kt into buffer sb. 2048 units of 16B; per wave-instr the
  // 64 lanes fill 1024B of LDS linearly (dest base wave-uniform).
  auto stage = [&](int sb, int kt) {
    const unsigned short* Kt = Kb + (size_t)(kt * 64) * HD;
    const unsigned short* Vtk = Vb + kt * 64;
#pragma unroll
    for (int i = 0; i < 4; ++i) {
      const int u = i * 256 + uA;
      const int key = u >> 4, cs = u & 15;
      g2l16(Kt + (size_t)key * HD + ((cs ^ (key & 7)) << 3),
            &Ks[sb][(i * 256 + w * 64) * 8]);
    }
#pragma unroll
    for (int i = 0; i < 4; ++i) {
      const int u = i * 256 + uA;
      const int d = u >> 3, cs = u & 7;
      g2l16(Vtk + (size_t)d * SEQ + ((cs ^ (d & 7)) << 3),
            &Vs[sb][(i * 256 + w * 64) * 8]);
    }
  };

  for (int half = 0; half < 2; ++half) {
    const int qt = half ? 31 - pr : pr;  // q-tile of 64 rows; kt = 0..qt

    // Q fragments: A-layout row = l15, k(hd) = ch*32 + quad*8
    bf16x8 qf[4];
#pragma unroll
    for (int ch = 0; ch < 4; ++ch)
      qf[ch] = *(const bf16x8*)(Qb + (size_t)(qt * 64 + w * 16 + l15) * HD +
                                ch * 32 + quad * 8);

    f32x4 o[8] = {};
    float mrow[4], lrow[4];
#pragma unroll
    for (int reg = 0; reg < 4; ++reg) { mrow[reg] = -1e30f; lrow[reg] = 0.f; }

    stage(0, 0);
    asm volatile("s_waitcnt vmcnt(0)\n\ts_barrier" ::: "memory");
    int buf = 0;

    for (int kt = 0; kt <= qt; ++kt) {
      if (kt < qt) stage(buf ^ 1, kt + 1);  // prefetch next tile

      // S = Q K^T (Q pre-scaled by log2e/sqrt(hd)). Diagonal tile: wave w
      // only needs key tiles nt <= w (rest fully masked).
      const bool diag = (kt == qt);
      const int ntm = diag ? w : 3;
      f32x4 s[4] = {};
      __builtin_amdgcn_s_setprio(1);
#pragma unroll
      for (int ch = 0; ch < 4; ++ch) {
        const int c = ch * 4 + quad;
#pragma unroll
        for (int nt = 0; nt < 4; ++nt) {
          if (nt <= ntm) {
            const int n = nt * 16 + l15;
            const bf16x8 bv = *(const bf16x8*)&Ks[buf][n * 128 + ((c ^ l7) << 3)];
            s[nt] = mfma16(qf[ch], bv, s[nt]);
          }
        }
      }
      __builtin_amdgcn_s_setprio(0);

      if (diag) {  // causal mask within 64x64 diagonal tile
#pragma unroll
        for (int nt = 0; nt < 4; ++nt)
#pragma unroll
          for (int reg = 0; reg < 4; ++reg) {
            const int rr = w * 16 + quad * 4 + reg;
            const int cc = nt * 16 + l15;
            if (cc > rr) s[nt][reg] = -1e30f;
          }
      }

      // online softmax in log2 domain, defer-max rescale (THR=8)
#pragma unroll
      for (int reg = 0; reg < 4; ++reg) {
        float vmax = s[0][reg];
#pragma unroll
        for (int nt = 1; nt < 4; ++nt) vmax = fmaxf(vmax, s[nt][reg]);
        vmax = red_max16(vmax);
        const float mo = mrow[reg];
        float mn = mo;
        if (!__all(vmax <= mo + 8.0f)) {  // wave-uniform branch
          mn = fmaxf(mo, vmax);
          const float alpha = exp2f(mo - mn);
          mrow[reg] = mn;
          lrow[reg] *= alpha;
#pragma unroll
          for (int nt = 0; nt < 8; ++nt) o[nt][reg] *= alpha;
        }
        float rs = 0.f;
#pragma unroll
        for (int nt = 0; nt < 4; ++nt) {
          const float p_ = exp2f(s[nt][reg] - mn);
          s[nt][reg] = p_;
          rs += p_;
        }
        rs = red_sum16(rs);
        lrow[reg] += rs;
      }

      // P -> wave-private LDS (no barrier needed; lgkm deps only).
      // Layout [plane=key>>3][row][8]: write (row=quad*4+reg, key=nt*16+l15),
      // read back as A-frag (row=l15, k=ch2*32+quad*8+e).
      unsigned short* Pw = Ps[w];
#pragma unroll
      for (int nt = 0; nt < 4; ++nt)
#pragma unroll
        for (int reg = 0; reg < 4; ++reg) {
          const int key = nt * 16 + l15;
          Pw[(key >> 3) * 128 + (quad * 4 + reg) * 8 + (key & 7)] = f2bf(s[nt][reg]);
        }

      // O += P V
      __builtin_amdgcn_s_setprio(1);
#pragma unroll
      for (int ch2 = 0; ch2 < 2; ++ch2) {
        const int c = ch2 * 4 + quad;
        const bf16x8 pa = *(const bf16x8*)&Pw[c * 128 + l15 * 8];
#pragma unroll
        for (int nt = 0; nt < 8; ++nt) {
          const int d = nt * 16 + l15;
          const bf16x8 vv = *(const bf16x8*)&Vs[buf][d * 64 + ((c ^ l7) << 3)];
          o[nt] = mfma16(pa, vv, o[nt]);
        }
      }
      __builtin_amdgcn_s_setprio(0);

      // single barrier per iter: next tile's loads (issued at top) now land.
      asm volatile("s_waitcnt vmcnt(0)\n\ts_barrier" ::: "memory");
      buf ^= 1;
    }

    // epilogue: normalize and store attn output as (B*S, D) bf16
#pragma unroll
    for (int reg = 0; reg < 4; ++reg) {
      const int sq = qt * 64 + w * 16 + quad * 4 + reg;
      const float inv_l = 1.0f / lrow[reg];
      unsigned short* ob = Oa + (size_t)(b * SEQ + sq) * DMODEL + h * HD;
#pragma unroll
      for (int nt = 0; nt < 8; ++nt) ob[nt * 16 + l15] = f2bf(o[nt][reg] * inv_l);
    }
  }
}

extern "C" void kernel_launch(void* const* d_in, const int* in_sizes, int n_in,
                              void* d_out, int out_size, void* d_ws, size_t ws_size,
                              hipStream_t stream) {
  const float* x = (const float*)d_in[0];
  const float* Wq = (const float*)d_in[1];
  const float* Wk = (const float*)d_in[2];
  const float* Wv = (const float*)d_in[3];
  const float* Wo = (const float*)d_in[4];
  float* out = (float*)d_out;

  const size_t NX = (size_t)2 * SEQ * DMODEL;
  const size_t NW = (size_t)DMODEL * DMODEL;
  unsigned short* ws = (unsigned short*)d_ws;
  unsigned short* xb = ws;
  unsigned short* wqb = xb + NX;   // wq/wk/wv contiguous -> fused N=6144 B operand
  unsigned short* wkb = wqb + NW;
  unsigned short* wvb = wkb + NW;
  unsigned short* wob = wvb + NW;
  unsigned short* qb = wob + NW;  // (B,H,S,hd) permuted-hd, rope'd, *log2e/sqrt(hd)
  unsigned short* kb = qb + NX;   // (B,H,S,hd) permuted-hd, rope'd
  unsigned short* vb = kb + NX;   // (B,H,hd,S)
  unsigned short* ab = vb + NX;   // (B*S, D)
  float2* rtab = (float2*)(ab + NX);  // 2048 x 64 cos/sin (1 MB)

  cvt_all<<<25088, 256, 0, stream>>>(x, Wq, Wk, Wv, Wo, ws, rtab);
  gemm_pipe<0><<<dim3(48, 16), 512, 0, stream>>>(xb, wqb, qb, nullptr, rtab);
  attn_kernel<<<512, 256, 0, stream>>>(qb, kb, vb, ab);
  gemm_pipe<1><<<dim3(16, 16), 512, 0, stream>>>(ab, wob, nullptr, out, nullptr);
}

// Round 4
// 374.264 us; speedup vs baseline: 1.1026x; 1.0077x over previous
//
#include <hip/hip_runtime.h>

// MHA forward: x(2,2048,2048) fp32, Wq/Wk/Wv/Wo (2048,2048) fp32 -> out fp32.
// R7: GEMM K-loop restructured to the m201 8-phase-style schedule:
//     per BK=64 tile, 2 phases of {ds_read frags || stage 3 loads ->
//     s_barrier -> lgkmcnt(0)+sched_barrier -> setprio(1) 16xMFMA setprio(0)
//     -> s_barrier}; 3-ring + vmcnt(6) once per tile (after 2nd cluster).
//     Bijective chunked XCD swizzle on linearized grid (768/256 blocks).
//     Attention (R6 pipelined flash) and cvt unchanged.

#define SEQ 2048
#define DMODEL 2048
#define NH 16
#define HD 128

typedef __attribute__((ext_vector_type(8))) short bf16x8;  // 8 bf16 = 4 VGPRs
typedef __attribute__((ext_vector_type(4))) float f32x4;

__device__ __forceinline__ unsigned short f2bf(float f) {  // RNE fp32->bf16
  unsigned int u = __float_as_uint(f);
  u += 0x7fffu + ((u >> 16) & 1u);
  return (unsigned short)(u >> 16);
}

__device__ __forceinline__ void g2l16(const void* g, void* l) {
  __builtin_amdgcn_global_load_lds((const __attribute__((address_space(1))) void*)g,
                                   (__attribute__((address_space(3))) void*)l,
                                   16, 0, 0);
}

__device__ __forceinline__ f32x4 mfma16(bf16x8 a, bf16x8 b, f32x4 c) {
  return __builtin_amdgcn_mfma_f32_16x16x32_bf16(a, b, c, 0, 0, 0);
}

template <int CTRL>
__device__ __forceinline__ float dpp_ror(float v) {
  return __int_as_float(__builtin_amdgcn_mov_dpp(__float_as_int(v), CTRL, 0xf, 0xf, false));
}
__device__ __forceinline__ float red_max16(float v) {
  v = fmaxf(v, dpp_ror<0x128>(v));
  v = fmaxf(v, dpp_ror<0x124>(v));
  v = fmaxf(v, dpp_ror<0x122>(v));
  v = fmaxf(v, dpp_ror<0x121>(v));
  return v;
}
__device__ __forceinline__ float red_sum16(float v) {
  v += dpp_ror<0x128>(v);
  v += dpp_ror<0x124>(v);
  v += dpp_ror<0x122>(v);
  v += dpp_ror<0x121>(v);
  return v;
}

// one launch: converts x + all four weights to bf16, permutes Wq/Wk rows
// within-head (RoPE pairs -> adjacent 16-col fragments), fills rope table.
__global__ __launch_bounds__(256) void cvt_all(const float* __restrict__ x,
                                               const float* __restrict__ wq,
                                               const float* __restrict__ wk,
                                               const float* __restrict__ wv,
                                               const float* __restrict__ wo,
                                               unsigned short* __restrict__ dst0,
                                               float2* __restrict__ rtab) {
  const int b = blockIdx.x;
  if (b >= 24576) {  // rope cos/sin table: 2048 x 64
    const int idx = (b - 24576) * 256 + threadIdx.x;  // [0, 131072)
    const int s = idx >> 6, d = idx & 63;
    float sn, cs;
    sincosf((float)s * exp2f(-0.20762050593046f * (float)d), &sn, &cs);
    rtab[idx] = make_float2(cs, sn);
    return;
  }
  const float* src;
  unsigned short* dst;
  int idx, r = -1;
  if (b < 8192) {  // x: 2097152 float4's
    src = x; dst = dst0; idx = b * 256 + threadIdx.x;
  } else {
    r = (b - 8192) >> 12;  // 4096 blocks per weight
    src = (r == 0) ? wq : (r == 1) ? wk : (r == 2) ? wv : wo;
    dst = dst0 + (size_t)2 * SEQ * DMODEL + (size_t)r * DMODEL * DMODEL;
    idx = ((b - 8192) & 4095) * 256 + threadIdx.x;
  }
  const float4 v = ((const float4*)src)[idx];
  ushort4 o;
  o.x = f2bf(v.x); o.y = f2bf(v.y); o.z = f2bf(v.z); o.w = f2bf(v.w);
  int widx = idx;
  if (r == 0 || r == 1) {  // permute Wq/Wk output-feature rows within head
    const int row = idx >> 9, col = idx & 511;
    const int o_ = row & 127;
    const int e = (((o_ >> 4) & 3) << 5) | (((o_ >> 6) & 1) << 4) | (o_ & 15);
    widx = (((row & ~127) | e) << 9) | col;
  }
  ((ushort4*)dst)[widx] = o;
}

// ---------------------------------------------------------------------------
// Pipelined GEMM core: C[m,n] = sum_k A[m,k]*B[n,k].
// BM=256, BN=128, BK=64. 512 threads = 8 waves (4M x 2N), wave tile 64x64.
// 3-deep LDS ring (144 KB), vmcnt(6) once per K-tile.
// Per tile: 2 phases of {8 ds_read frags || 3 stage loads -> s_barrier ->
// lgkmcnt(0)+sched_barrier -> setprio(1) 16 MFMA setprio(0) -> s_barrier}.
// Grid linearized + chunked XCD swizzle (G%8==0 -> bijective).
// MODE 0: fused QKV (N=6144, 768 blocks); MODE 1: attn@Wo^T (256 blocks).
// ---------------------------------------------------------------------------
template <int MODE>
__global__ __launch_bounds__(512, 2) void gemm_pipe(
    const unsigned short* __restrict__ A,
    const unsigned short* __restrict__ B,
    unsigned short* __restrict__ obf,   // MODE0: qb (kb=+NX, vb=+2NX)
    float* __restrict__ of32,           // MODE1: output
    const float2* __restrict__ rtab) {
  __shared__ unsigned short lds[3 * 24576];  // 147456 B
  const int NBX = (MODE == 0) ? 48 : 16;
  const int G = (MODE == 0) ? 768 : 256;
  const int bid = blockIdx.x;
  const int lin = (bid & 7) * (G >> 3) + (bid >> 3);  // XCD-chunked swizzle
  const int nb = lin % NBX, mb = lin / NBX;
  const int M0 = mb * 256;
  const int t = threadIdx.x;
  const int w = t >> 6, lane = t & 63, l15 = lane & 15, quad = lane >> 4;
  const int g = lane >> 3, j = lane & 7;
  const int wm = w >> 1, wn = w & 1;

  const unsigned short* Abase = A + (size_t)M0 * DMODEL;
  const unsigned short* Bbase = B + (size_t)nb * 128 * DMODEL;

  f32x4 acc[4][4] = {};

  // stage 3 of this wave's 6 units for one tile. units: 0..31 A (8 rows each),
  // 32..47 B. dest linear [8 rows][8 chunks][16B]; src chunk pre-swizzled j^g.
  auto stage = [&](int buf, int k0, int i0) {
#pragma unroll
    for (int i = 0; i < 3; ++i) {
      const int u = w * 6 + i0 + i;
      if (u < 32) {
        const int row = u * 8 + g;
        g2l16(Abase + (size_t)row * DMODEL + k0 + ((j ^ g) << 3),
              &lds[buf * 24576 + u * 512]);
      } else {
        const int row = (u - 32) * 8 + g;
        g2l16(Bbase + (size_t)row * DMODEL + k0 + ((j ^ g) << 3),
              &lds[buf * 24576 + 16384 + (u - 32) * 512]);
      }
    }
  };

  // one phase: frag reads + optional stage-half, then aligned MFMA cluster.
  auto phase = [&](int buf, int kc, bool dostage, int b2, int k2) {
    const int c = kc * 4 + quad;
    const unsigned short* As_ = &lds[buf * 24576];
    const unsigned short* Bs_ = &lds[buf * 24576 + 16384];
    bf16x8 af[4], bv[4];
#pragma unroll
    for (int mt = 0; mt < 4; ++mt) {
      const int m = wm * 64 + mt * 16 + l15;
      af[mt] = *(const bf16x8*)&As_[m * 64 + ((c ^ (m & 7)) << 3)];
    }
#pragma unroll
    for (int nt = 0; nt < 4; ++nt) {
      const int n = wn * 64 + nt * 16 + l15;
      bv[nt] = *(const bf16x8*)&Bs_[n * 64 + ((c ^ (n & 7)) << 3)];
    }
    if (dostage) stage(b2, k2, kc * 3);
    __builtin_amdgcn_s_barrier();
    asm volatile("s_waitcnt lgkmcnt(0)" ::: "memory");
    __builtin_amdgcn_sched_barrier(0);
    __builtin_amdgcn_s_setprio(1);
#pragma unroll
    for (int nt = 0; nt < 4; ++nt)
#pragma unroll
      for (int mt = 0; mt < 4; ++mt)
        acc[mt][nt] = mfma16(af[mt], bv[nt], acc[mt][nt]);
    __builtin_amdgcn_s_setprio(0);
  };

  // prologue: tiles 0 and 1 in flight (12 loads); wait tile 0 (6 remain)
  stage(0, 0, 0);
  stage(0, 0, 3);
  stage(1, 64, 0);
  stage(1, 64, 3);
  asm volatile("s_waitcnt vmcnt(6)\n\ts_barrier" ::: "memory");

  int buf = 0, b2 = 2;
  for (int tt = 0; tt < 32; ++tt) {
    const int k2 = tt * 64 + 128;
    const bool ds = (tt < 30);
    phase(buf, 0, ds, b2, k2);
    __builtin_amdgcn_s_barrier();
    phase(buf, 1, ds, b2, k2);
    if (ds) {
      asm volatile("s_waitcnt vmcnt(6)" ::: "memory");
    } else if (tt == 30) {
      asm volatile("s_waitcnt vmcnt(0)" ::: "memory");
    }
    if (tt < 31) __builtin_amdgcn_s_barrier();
    buf = (buf == 2) ? 0 : buf + 1;
    b2 = (b2 == 2) ? 0 : b2 + 1;
  }

  // Epilogue. C/D layout: col = l15 (N side), row = quad*4 + reg (M side).
  if (MODE == 0) {
    const size_t NX = (size_t)2 * SEQ * DMODEL;
    const int z = nb >> 4;  // 0:Q 1:K 2:V (BN=128 == one head)
    const int h = nb & 15;
    if (z < 2) {
      const float qscale = (z == 0) ? 0.1275174356f : 1.0f;
      unsigned short* O = obf + (size_t)z * NX;
#pragma unroll
      for (int mt = 0; mt < 4; ++mt)
#pragma unroll
        for (int reg = 0; reg < 4; ++reg) {
          const int m = M0 + wm * 64 + mt * 16 + quad * 4 + reg;
          const int bb = m >> 11, s = m & 2047;
          unsigned short* ob = O + ((size_t)(bb * NH + h) * SEQ + s) * HD;
#pragma unroll
          for (int p = 0; p < 2; ++p) {
            const int q = wn * 2 + p;
            const float2 cs = rtab[s * 64 + q * 16 + l15];
            const float x1 = acc[mt][2 * p][reg], x2 = acc[mt][2 * p + 1][reg];
            ob[wn * 64 + (2 * p) * 16 + l15] = f2bf((x1 * cs.x - x2 * cs.y) * qscale);
            ob[wn * 64 + (2 * p + 1) * 16 + l15] = f2bf((x2 * cs.x + x1 * cs.y) * qscale);
          }
        }
    } else {
      unsigned short* Vb = obf + 2 * NX + (size_t)h * HD * SEQ;
#pragma unroll
      for (int mt = 0; mt < 4; ++mt)
#pragma unroll
        for (int reg = 0; reg < 4; ++reg) {
          const int m = M0 + wm * 64 + mt * 16 + quad * 4 + reg;
          const int bb = m >> 11, s = m & 2047;
          unsigned short* ob = Vb + (size_t)bb * NH * HD * SEQ;
#pragma unroll
          for (int nt = 0; nt < 4; ++nt)
            ob[(size_t)(wn * 64 + nt * 16 + l15) * SEQ + s] = f2bf(acc[mt][nt][reg]);
        }
    }
  } else {
#pragma unroll
    for (int mt = 0; mt < 4; ++mt)
#pragma unroll
      for (int reg = 0; reg < 4; ++reg) {
        const int m = M0 + wm * 64 + mt * 16 + quad * 4 + reg;
#pragma unroll
        for (int nt = 0; nt < 4; ++nt)
          of32[(size_t)m * DMODEL + nb * 128 + wn * 64 + nt * 16 + l15] =
              acc[mt][nt][reg];
      }
  }
}

// ---------------------------------------------------------------------------
// Flash attention, causal. QBLK=64, KVBLK=64, double-buffered K/V.
// Block = one (b,h) x q-tile pair (p, 31-p): (p+1)+(32-p) = 33 kt-iters for
// every block (perfect balance). Grid 512 = 2 blocks/CU (72 KB LDS each).
// Per iter: stage(kt+1 -> buf^1) ; QK^T(buf) ; softmax ; P->wave-private LDS
// (no barrier) ; PV(buf) ; vmcnt(0)+s_barrier (loads issued a full iteration
// earlier -> latency hidden). One barrier per iteration, never a cold drain.
// ---------------------------------------------------------------------------
__global__ __launch_bounds__(256) void attn_kernel(const unsigned short* __restrict__ Q,
                                                   const unsigned short* __restrict__ K,
                                                   const unsigned short* __restrict__ Vt,
                                                   unsigned short* __restrict__ Oa) {
  __shared__ unsigned short Ks[2][64 * 128];  // 2 x 16 KB
  __shared__ unsigned short Vs[2][128 * 64];  // 2 x 16 KB
  __shared__ unsigned short Ps[4][1024];      // 4 x 2 KB wave-private P
  const int gid = blockIdx.x;
  const int bh = gid & 31;  // all 16 pair-blocks of one bh on XCD bh%8
  const int pr = gid >> 5;  // pair index 0..15
  const unsigned short* Qb = Q + (size_t)bh * SEQ * HD;
  const unsigned short* Kb = K + (size_t)bh * SEQ * HD;
  const unsigned short* Vb = Vt + (size_t)bh * HD * SEQ;
  const int t = threadIdx.x;
  const int w = t >> 6, lane = t & 63, l15 = lane & 15, quad = lane >> 4;
  const int l7 = lane & 7;
  const int b = bh >> 4, h = bh & 15;
  const int uA = w * 64 + lane;  // staging unit base (i*256 added per instr)

  auto stage = [&](int sb, int kt) {
    const unsigned short* Kt = Kb + (size_t)(kt * 64) * HD;
    const unsigned short* Vtk = Vb + kt * 64;
#pragma unroll
    for (int i = 0; i < 4; ++i) {
      const int u = i * 256 + uA;
      const int key = u >> 4, cs = u & 15;
      g2l16(Kt + (size_t)key * HD + ((cs ^ (key & 7)) << 3),
            &Ks[sb][(i * 256 + w * 64) * 8]);
    }
#pragma unroll
    for (int i = 0; i < 4; ++i) {
      const int u = i * 256 + uA;
      const int d = u >> 3, cs = u & 7;
      g2l16(Vtk + (size_t)d * SEQ + ((cs ^ (d & 7)) << 3),
            &Vs[sb][(i * 256 + w * 64) * 8]);
    }
  };

  for (int half = 0; half < 2; ++half) {
    const int qt = half ? 31 - pr : pr;  // q-tile of 64 rows; kt = 0..qt

    // Q fragments: A-layout row = l15, k(hd) = ch*32 + quad*8
    bf16x8 qf[4];
#pragma unroll
    for (int ch = 0; ch < 4; ++ch)
      qf[ch] = *(const bf16x8*)(Qb + (size_t)(qt * 64 + w * 16 + l15) * HD +
                                ch * 32 + quad * 8);

    f32x4 o[8] = {};
    float mrow[4], lrow[4];
#pragma unroll
    for (int reg = 0; reg < 4; ++reg) { mrow[reg] = -1e30f; lrow[reg] = 0.f; }

    stage(0, 0);
    asm volatile("s_waitcnt vmcnt(0)\n\ts_barrier" ::: "memory");
    int buf = 0;

    for (int kt = 0; kt <= qt; ++kt) {
      if (kt < qt) stage(buf ^ 1, kt + 1);  // prefetch next tile

      // S = Q K^T (Q pre-scaled by log2e/sqrt(hd)). Diagonal tile: wave w
      // only needs key tiles nt <= w (rest fully masked).
      const bool diag = (kt == qt);
      const int ntm = diag ? w : 3;
      f32x4 s[4] = {};
      __builtin_amdgcn_s_setprio(1);
#pragma unroll
      for (int ch = 0; ch < 4; ++ch) {
        const int c = ch * 4 + quad;
#pragma unroll
        for (int nt = 0; nt < 4; ++nt) {
          if (nt <= ntm) {
            const int n = nt * 16 + l15;
            const bf16x8 bv = *(const bf16x8*)&Ks[buf][n * 128 + ((c ^ l7) << 3)];
            s[nt] = mfma16(qf[ch], bv, s[nt]);
          }
        }
      }
      __builtin_amdgcn_s_setprio(0);

      if (diag) {  // causal mask within 64x64 diagonal tile
#pragma unroll
        for (int nt = 0; nt < 4; ++nt)
#pragma unroll
          for (int reg = 0; reg < 4; ++reg) {
            const int rr = w * 16 + quad * 4 + reg;
            const int cc = nt * 16 + l15;
            if (cc > rr) s[nt][reg] = -1e30f;
          }
      }

      // online softmax in log2 domain, defer-max rescale (THR=8)
#pragma unroll
      for (int reg = 0; reg < 4; ++reg) {
        float vmax = s[0][reg];
#pragma unroll
        for (int nt = 1; nt < 4; ++nt) vmax = fmaxf(vmax, s[nt][reg]);
        vmax = red_max16(vmax);
        const float mo = mrow[reg];
        float mn = mo;
        if (!__all(vmax <= mo + 8.0f)) {  // wave-uniform branch
          mn = fmaxf(mo, vmax);
          const float alpha = exp2f(mo - mn);
          mrow[reg] = mn;
          lrow[reg] *= alpha;
#pragma unroll
          for (int nt = 0; nt < 8; ++nt) o[nt][reg] *= alpha;
        }
        float rs = 0.f;
#pragma unroll
        for (int nt = 0; nt < 4; ++nt) {
          const float p_ = exp2f(s[nt][reg] - mn);
          s[nt][reg] = p_;
          rs += p_;
        }
        rs = red_sum16(rs);
        lrow[reg] += rs;
      }

      // P -> wave-private LDS (no barrier needed; lgkm deps only).
      unsigned short* Pw = Ps[w];
#pragma unroll
      for (int nt = 0; nt < 4; ++nt)
#pragma unroll
        for (int reg = 0; reg < 4; ++reg) {
          const int key = nt * 16 + l15;
          Pw[(key >> 3) * 128 + (quad * 4 + reg) * 8 + (key & 7)] = f2bf(s[nt][reg]);
        }

      // O += P V
      __builtin_amdgcn_s_setprio(1);
#pragma unroll
      for (int ch2 = 0; ch2 < 2; ++ch2) {
        const int c = ch2 * 4 + quad;
        const bf16x8 pa = *(const bf16x8*)&Pw[c * 128 + l15 * 8];
#pragma unroll
        for (int nt = 0; nt < 8; ++nt) {
          const int d = nt * 16 + l15;
          const bf16x8 vv = *(const bf16x8*)&Vs[buf][d * 64 + ((c ^ l7) << 3)];
          o[nt] = mfma16(pa, vv, o[nt]);
        }
      }
      __builtin_amdgcn_s_setprio(0);

      // single barrier per iter: next tile's loads (issued at top) now land.
      asm volatile("s_waitcnt vmcnt(0)\n\ts_barrier" ::: "memory");
      buf ^= 1;
    }

    // epilogue: normalize and store attn output as (B*S, D) bf16
#pragma unroll
    for (int reg = 0; reg < 4; ++reg) {
      const int sq = qt * 64 + w * 16 + quad * 4 + reg;
      const float inv_l = 1.0f / lrow[reg];
      unsigned short* ob = Oa + (size_t)(b * SEQ + sq) * DMODEL + h * HD;
#pragma unroll
      for (int nt = 0; nt < 8; ++nt) ob[nt * 16 + l15] = f2bf(o[nt][reg] * inv_l);
    }
  }
}

extern "C" void kernel_launch(void* const* d_in, const int* in_sizes, int n_in,
                              void* d_out, int out_size, void* d_ws, size_t ws_size,
                              hipStream_t stream) {
  const float* x = (const float*)d_in[0];
  const float* Wq = (const float*)d_in[1];
  const float* Wk = (const float*)d_in[2];
  const float* Wv = (const float*)d_in[3];
  const float* Wo = (const float*)d_in[4];
  float* out = (float*)d_out;

  const size_t NX = (size_t)2 * SEQ * DMODEL;
  const size_t NW = (size_t)DMODEL * DMODEL;
  unsigned short* ws = (unsigned short*)d_ws;
  unsigned short* xb = ws;
  unsigned short* wqb = xb + NX;   // wq/wk/wv contiguous -> fused N=6144 B operand
  unsigned short* wkb = wqb + NW;
  unsigned short* wvb = wkb + NW;
  unsigned short* wob = wvb + NW;
  unsigned short* qb = wob + NW;  // (B,H,S,hd) permuted-hd, rope'd, *log2e/sqrt(hd)
  unsigned short* kb = qb + NX;   // (B,H,S,hd) permuted-hd, rope'd
  unsigned short* vb = kb + NX;   // (B,H,hd,S)
  unsigned short* ab = vb + NX;   // (B*S, D)
  float2* rtab = (float2*)(ab + NX);  // 2048 x 64 cos/sin (1 MB)

  cvt_all<<<25088, 256, 0, stream>>>(x, Wq, Wk, Wv, Wo, ws, rtab);
  gemm_pipe<0><<<768, 512, 0, stream>>>(xb, wqb, qb, nullptr, rtab);
  attn_kernel<<<512, 256, 0, stream>>>(qb, kb, vb, ab);
  gemm_pipe<1><<<256, 512, 0, stream>>>(ab, wob, nullptr, out, nullptr);
}

// Round 5
// 356.660 us; speedup vs baseline: 1.1571x; 1.0494x over previous
//
#include <hip/hip_runtime.h>

// MHA forward: x(2,2048,2048) fp32, Wq/Wk/Wv/Wo (2048,2048) fp32 -> out fp32.
// R8: revert R7 (XCD swizzle streamed whole B per XCD -> FETCH 119->214MB;
//     phase-split barriers dropped MfmaUtil). Natural dim3 order restored
//     (gridDim.x%8==0 -> fixed nb-mod-8 per XCD, B panels L2-resident).
//     GEMM MODE0 geometry: BM=256 BN=192 (wave 64x96, acc 4x6), ring-2
//     (112 KB), exact 2-round grid 32x16. LDS traffic/FLOP x0.82.
//     MODE1 stays BM=256 BN=128 (exact 1-round grid 16x16).
//     Attention (R6 pipelined flash) and cvt unchanged.

#define SEQ 2048
#define DMODEL 2048
#define NH 16
#define HD 128

typedef __attribute__((ext_vector_type(8))) short bf16x8;  // 8 bf16 = 4 VGPRs
typedef __attribute__((ext_vector_type(4))) float f32x4;

__device__ __forceinline__ unsigned short f2bf(float f) {  // RNE fp32->bf16
  unsigned int u = __float_as_uint(f);
  u += 0x7fffu + ((u >> 16) & 1u);
  return (unsigned short)(u >> 16);
}

__device__ __forceinline__ void g2l16(const void* g, void* l) {
  __builtin_amdgcn_global_load_lds((const __attribute__((address_space(1))) void*)g,
                                   (__attribute__((address_space(3))) void*)l,
                                   16, 0, 0);
}

__device__ __forceinline__ f32x4 mfma16(bf16x8 a, bf16x8 b, f32x4 c) {
  return __builtin_amdgcn_mfma_f32_16x16x32_bf16(a, b, c, 0, 0, 0);
}

template <int CTRL>
__device__ __forceinline__ float dpp_ror(float v) {
  return __int_as_float(__builtin_amdgcn_mov_dpp(__float_as_int(v), CTRL, 0xf, 0xf, false));
}
__device__ __forceinline__ float red_max16(float v) {
  v = fmaxf(v, dpp_ror<0x128>(v));
  v = fmaxf(v, dpp_ror<0x124>(v));
  v = fmaxf(v, dpp_ror<0x122>(v));
  v = fmaxf(v, dpp_ror<0x121>(v));
  return v;
}
__device__ __forceinline__ float red_sum16(float v) {
  v += dpp_ror<0x128>(v);
  v += dpp_ror<0x124>(v);
  v += dpp_ror<0x122>(v);
  v += dpp_ror<0x121>(v);
  return v;
}

// one launch: converts x + all four weights to bf16, permutes Wq/Wk rows
// within-head (RoPE pairs -> adjacent 16-col fragments), fills rope table.
// Permutation (head-local output feature o in [0,128)):
//   e = ((o>>4)&3)*32 + ((o>>6)&1)*16 + (o&15)
// so orig pair (d, d+64) lands at new cols (q*32+r, q*32+16+r), q=d>>4, r=d&15.
__global__ __launch_bounds__(256) void cvt_all(const float* __restrict__ x,
                                               const float* __restrict__ wq,
                                               const float* __restrict__ wk,
                                               const float* __restrict__ wv,
                                               const float* __restrict__ wo,
                                               unsigned short* __restrict__ dst0,
                                               float2* __restrict__ rtab) {
  const int b = blockIdx.x;
  if (b >= 24576) {  // rope cos/sin table: 2048 x 64
    const int idx = (b - 24576) * 256 + threadIdx.x;  // [0, 131072)
    const int s = idx >> 6, d = idx & 63;
    float sn, cs;
    sincosf((float)s * exp2f(-0.20762050593046f * (float)d), &sn, &cs);
    rtab[idx] = make_float2(cs, sn);
    return;
  }
  const float* src;
  unsigned short* dst;
  int idx, r = -1;
  if (b < 8192) {  // x: 2097152 float4's
    src = x; dst = dst0; idx = b * 256 + threadIdx.x;
  } else {
    r = (b - 8192) >> 12;  // 4096 blocks per weight
    src = (r == 0) ? wq : (r == 1) ? wk : (r == 2) ? wv : wo;
    dst = dst0 + (size_t)2 * SEQ * DMODEL + (size_t)r * DMODEL * DMODEL;
    idx = ((b - 8192) & 4095) * 256 + threadIdx.x;
  }
  const float4 v = ((const float4*)src)[idx];
  ushort4 o;
  o.x = f2bf(v.x); o.y = f2bf(v.y); o.z = f2bf(v.z); o.w = f2bf(v.w);
  int widx = idx;
  if (r == 0 || r == 1) {  // permute Wq/Wk output-feature rows within head
    const int row = idx >> 9, col = idx & 511;
    const int o_ = row & 127;
    const int e = (((o_ >> 4) & 3) << 5) | (((o_ >> 6) & 1) << 4) | (o_ & 15);
    widx = (((row & ~127) | e) << 9) | col;
  }
  ((ushort4*)dst)[widx] = o;
}

// ---------------------------------------------------------------------------
// Pipelined GEMM core: C[m,n] = sum_k A[m,k]*B[n,k].
// BM=256, BN=192(MODE0)/128(MODE1), BK=64. 512 threads = 8 waves (4M x 2N),
// wave tile 64 x BN/2. Ring-2 LDS double-buffer; R6 counted-latency schedule:
// stage tile t+1 at top of t (interleaved with the two compute phases), one
// vmcnt(0)+s_barrier at tile end (loads had a full tile to land).
// Natural dim3 grid: gridDim.x % 8 == 0 -> each XCD owns fixed nb mod 8
// (B panels L2-resident); do NOT linearize/swizzle (R7 regression).
// MODE 0: fused QKV (N=6144, grid 32x16 = exact 2 rounds);
// MODE 1: attn_out @ Wo^T, fp32 (grid 16x16 = exact 1 round).
// ---------------------------------------------------------------------------
template <int MODE>
__global__ __launch_bounds__(512, 2) void gemm_pipe(
    const unsigned short* __restrict__ A,
    const unsigned short* __restrict__ B,
    unsigned short* __restrict__ obf,   // MODE0: qb (kb=+NX, vb=+2NX)
    float* __restrict__ of32,           // MODE1: output
    const float2* __restrict__ rtab) {
  constexpr int BN = (MODE == 0) ? 192 : 128;
  constexpr int NTW = BN / 32;            // B frags per wave: 6 / 4
  constexpr int TILE = (256 + BN) * 64;   // shorts per ring buffer
  constexpr int NU = 32 + BN / 8;         // staging units: 56 / 48
  constexpr int UPW = NU / 8;             // units per wave: 7 / 6
  __shared__ unsigned short lds[2 * TILE];
  const int nb = blockIdx.x, mb = blockIdx.y;
  const int M0 = mb * 256;
  const int t = threadIdx.x;
  const int w = t >> 6, lane = t & 63, l15 = lane & 15, quad = lane >> 4;
  const int g = lane >> 3, j = lane & 7;
  const int wm = w >> 1, wn = w & 1;

  const unsigned short* Abase = A + (size_t)M0 * DMODEL;
  const unsigned short* Bbase = B + (size_t)nb * BN * DMODEL;

  f32x4 acc[4][NTW] = {};

  // stage units [i0,i1) of this wave's UPW units for one tile.
  // units: 0..31 A (8 rows each), 32.. B. dest linear [8 rows][8 chunks][16B];
  // src chunk pre-swizzled j^g so LDS slot s holds global chunk s^g.
  auto stage = [&](int buf, int k0, int i0, int i1) {
#pragma unroll
    for (int i = i0; i < i1; ++i) {
      const int u = w * UPW + i;
      if (u < 32) {
        g2l16(Abase + (size_t)(u * 8 + g) * DMODEL + k0 + ((j ^ g) << 3),
              &lds[buf * TILE + u * 512]);
      } else {
        g2l16(Bbase + (size_t)((u - 32) * 8 + g) * DMODEL + k0 + ((j ^ g) << 3),
              &lds[buf * TILE + 16384 + (u - 32) * 512]);
      }
    }
  };

  // one kc half (K=32): 4+NTW ds_read_b128 + 4*NTW MFMA
  auto comp = [&](int buf, int kc) {
    const int c = kc * 4 + quad;
    const unsigned short* As_ = &lds[buf * TILE];
    const unsigned short* Bs_ = &lds[buf * TILE + 16384];
    bf16x8 af[4], bv[NTW];
#pragma unroll
    for (int mt = 0; mt < 4; ++mt) {
      const int m = wm * 64 + mt * 16 + l15;
      af[mt] = *(const bf16x8*)&As_[m * 64 + ((c ^ (m & 7)) << 3)];
    }
#pragma unroll
    for (int nt = 0; nt < NTW; ++nt) {
      const int n = wn * (BN / 2) + nt * 16 + l15;
      bv[nt] = *(const bf16x8*)&Bs_[n * 64 + ((c ^ (n & 7)) << 3)];
    }
#pragma unroll
    for (int nt = 0; nt < NTW; ++nt)
#pragma unroll
      for (int mt = 0; mt < 4; ++mt)
        acc[mt][nt] = mfma16(af[mt], bv[nt], acc[mt][nt]);
  };

  stage(0, 0, 0, UPW);
  asm volatile("s_waitcnt vmcnt(0)\n\ts_barrier" ::: "memory");

  int buf = 0;
  for (int tt = 0; tt < 32; ++tt) {
    const bool ps = (tt < 31);
    if (ps) stage(buf ^ 1, tt * 64 + 64, 0, UPW / 2);
    comp(buf, 0);
    if (ps) stage(buf ^ 1, tt * 64 + 64, UPW / 2, UPW);
    comp(buf, 1);
    if (ps) {
      asm volatile("s_waitcnt vmcnt(0)\n\ts_barrier" ::: "memory");
      buf ^= 1;
    }
  }

  // Epilogue. C/D layout: col = l15 (N side), row = quad*4 + reg (M side).
  if (MODE == 0) {
    const size_t NX = (size_t)2 * SEQ * DMODEL;
    // process N in 32-col pairs (frags 2pp, 2pp+1); 32 | 2048 so a pair never
    // straddles the Q/K/V or head boundary; 96 % 32 == 0 keeps pairs aligned.
#pragma unroll
    for (int pp = 0; pp < NTW / 2; ++pp) {
      const int colb = nb * BN + wn * (BN / 2) + pp * 32;  // 32-aligned
      const int z = colb >> 11;          // 0:Q 1:K 2:V
      const int zc = colb & 2047;
      const int h = zc >> 7;             // head
      const int e0 = zc & 127;           // in-head col base (0/32/64/96)
      if (z < 2) {
        const float qscale = (z == 0) ? 0.1275174356f : 1.0f;
        unsigned short* O = obf + (size_t)z * NX;
        const int rt = (e0 >> 5) * 16 + l15;  // rope dim q*16 + r
#pragma unroll
        for (int mt = 0; mt < 4; ++mt)
#pragma unroll
          for (int reg = 0; reg < 4; ++reg) {
            const int m = M0 + wm * 64 + mt * 16 + quad * 4 + reg;
            const int bb = m >> 11, s = m & 2047;
            unsigned short* ob = O + ((size_t)(bb * NH + h) * SEQ + s) * HD;
            const float2 cs = rtab[s * 64 + rt];
            const float x1 = acc[mt][2 * pp][reg], x2 = acc[mt][2 * pp + 1][reg];
            ob[e0 + l15] = f2bf((x1 * cs.x - x2 * cs.y) * qscale);
            ob[e0 + 16 + l15] = f2bf((x2 * cs.x + x1 * cs.y) * qscale);
          }
      } else {
        // V stored transposed: (B,H,hd,S), natural (unpermuted) d
        unsigned short* Vb0 = obf + 2 * NX + (size_t)h * HD * SEQ;
#pragma unroll
        for (int q2 = 0; q2 < 2; ++q2) {
          const int d = e0 + q2 * 16 + l15;
#pragma unroll
          for (int mt = 0; mt < 4; ++mt)
#pragma unroll
            for (int reg = 0; reg < 4; ++reg) {
              const int m = M0 + wm * 64 + mt * 16 + quad * 4 + reg;
              const int bb = m >> 11, s = m & 2047;
              unsigned short* ob = Vb0 + (size_t)bb * NH * HD * SEQ;
              ob[(size_t)d * SEQ + s] = f2bf(acc[mt][2 * pp + q2][reg]);
            }
        }
      }
    }
  } else {
#pragma unroll
    for (int mt = 0; mt < 4; ++mt)
#pragma unroll
      for (int reg = 0; reg < 4; ++reg) {
        const int m = M0 + wm * 64 + mt * 16 + quad * 4 + reg;
#pragma unroll
        for (int nt = 0; nt < NTW; ++nt)
          of32[(size_t)m * DMODEL + nb * BN + wn * (BN / 2) + nt * 16 + l15] =
              acc[mt][nt][reg];
      }
  }
}

// ---------------------------------------------------------------------------
// Flash attention, causal. QBLK=64, KVBLK=64, double-buffered K/V.
// Block = one (b,h) x q-tile pair (p, 31-p): (p+1)+(32-p) = 33 kt-iters for
// every block (perfect balance). Grid 512 = 2 blocks/CU (72 KB LDS each).
// Per iter: stage(kt+1 -> buf^1) ; QK^T(buf) ; softmax ; P->wave-private LDS
// (no barrier) ; PV(buf) ; vmcnt(0)+s_barrier (loads issued a full iteration
// earlier -> latency hidden). One barrier per iteration, never a cold drain.
// ---------------------------------------------------------------------------
__global__ __launch_bounds__(256) void attn_kernel(const unsigned short* __restrict__ Q,
                                                   const unsigned short* __restrict__ K,
                                                   const unsigned short* __restrict__ Vt,
                                                   unsigned short* __restrict__ Oa) {
  __shared__ unsigned short Ks[2][64 * 128];  // 2 x 16 KB
  __shared__ unsigned short Vs[2][128 * 64];  // 2 x 16 KB
  __shared__ unsigned short Ps[4][1024];      // 4 x 2 KB wave-private P
  const int gid = blockIdx.x;
  const int bh = gid & 31;  // all 16 pair-blocks of one bh on XCD bh%8
  const int pr = gid >> 5;  // pair index 0..15
  const unsigned short* Qb = Q + (size_t)bh * SEQ * HD;
  const unsigned short* Kb = K + (size_t)bh * SEQ * HD;
  const unsigned short* Vb = Vt + (size_t)bh * HD * SEQ;
  const int t = threadIdx.x;
  const int w = t >> 6, lane = t & 63, l15 = lane & 15, quad = lane >> 4;
  const int l7 = lane & 7;
  const int b = bh >> 4, h = bh & 15;
  const int uA = w * 64 + lane;  // staging unit base (i*256 added per instr)

  auto stage = [&](int sb, int kt) {
    const unsigned short* Kt = Kb + (size_t)(kt * 64) * HD;
    const unsigned short* Vtk = Vb + kt * 64;
#pragma unroll
    for (int i = 0; i < 4; ++i) {
      const int u = i * 256 + uA;
      const int key = u >> 4, cs = u & 15;
      g2l16(Kt + (size_t)key * HD + ((cs ^ (key & 7)) << 3),
            &Ks[sb][(i * 256 + w * 64) * 8]);
    }
#pragma unroll
    for (int i = 0; i < 4; ++i) {
      const int u = i * 256 + uA;
      const int d = u >> 3, cs = u & 7;
      g2l16(Vtk + (size_t)d * SEQ + ((cs ^ (d & 7)) << 3),
            &Vs[sb][(i * 256 + w * 64) * 8]);
    }
  };

  for (int half = 0; half < 2; ++half) {
    const int qt = half ? 31 - pr : pr;  // q-tile of 64 rows; kt = 0..qt

    // Q fragments: A-layout row = l15, k(hd) = ch*32 + quad*8
    bf16x8 qf[4];
#pragma unroll
    for (int ch = 0; ch < 4; ++ch)
      qf[ch] = *(const bf16x8*)(Qb + (size_t)(qt * 64 + w * 16 + l15) * HD +
                                ch * 32 + quad * 8);

    f32x4 o[8] = {};
    float mrow[4], lrow[4];
#pragma unroll
    for (int reg = 0; reg < 4; ++reg) { mrow[reg] = -1e30f; lrow[reg] = 0.f; }

    stage(0, 0);
    asm volatile("s_waitcnt vmcnt(0)\n\ts_barrier" ::: "memory");
    int buf = 0;

    for (int kt = 0; kt <= qt; ++kt) {
      if (kt < qt) stage(buf ^ 1, kt + 1);  // prefetch next tile

      // S = Q K^T (Q pre-scaled by log2e/sqrt(hd)). Diagonal tile: wave w
      // only needs key tiles nt <= w (rest fully masked).
      const bool diag = (kt == qt);
      const int ntm = diag ? w : 3;
      f32x4 s[4] = {};
      __builtin_amdgcn_s_setprio(1);
#pragma unroll
      for (int ch = 0; ch < 4; ++ch) {
        const int c = ch * 4 + quad;
#pragma unroll
        for (int nt = 0; nt < 4; ++nt) {
          if (nt <= ntm) {
            const int n = nt * 16 + l15;
            const bf16x8 bv = *(const bf16x8*)&Ks[buf][n * 128 + ((c ^ l7) << 3)];
            s[nt] = mfma16(qf[ch], bv, s[nt]);
          }
        }
      }
      __builtin_amdgcn_s_setprio(0);

      if (diag) {  // causal mask within 64x64 diagonal tile
#pragma unroll
        for (int nt = 0; nt < 4; ++nt)
#pragma unroll
          for (int reg = 0; reg < 4; ++reg) {
            const int rr = w * 16 + quad * 4 + reg;
            const int cc = nt * 16 + l15;
            if (cc > rr) s[nt][reg] = -1e30f;
          }
      }

      // online softmax in log2 domain, defer-max rescale (THR=8)
#pragma unroll
      for (int reg = 0; reg < 4; ++reg) {
        float vmax = s[0][reg];
#pragma unroll
        for (int nt = 1; nt < 4; ++nt) vmax = fmaxf(vmax, s[nt][reg]);
        vmax = red_max16(vmax);
        const float mo = mrow[reg];
        float mn = mo;
        if (!__all(vmax <= mo + 8.0f)) {  // wave-uniform branch
          mn = fmaxf(mo, vmax);
          const float alpha = exp2f(mo - mn);
          mrow[reg] = mn;
          lrow[reg] *= alpha;
#pragma unroll
          for (int nt = 0; nt < 8; ++nt) o[nt][reg] *= alpha;
        }
        float rs = 0.f;
#pragma unroll
        for (int nt = 0; nt < 4; ++nt) {
          const float p_ = exp2f(s[nt][reg] - mn);
          s[nt][reg] = p_;
          rs += p_;
        }
        rs = red_sum16(rs);
        lrow[reg] += rs;
      }

      // P -> wave-private LDS (no barrier needed; lgkm deps only).
      unsigned short* Pw = Ps[w];
#pragma unroll
      for (int nt = 0; nt < 4; ++nt)
#pragma unroll
        for (int reg = 0; reg < 4; ++reg) {
          const int key = nt * 16 + l15;
          Pw[(key >> 3) * 128 + (quad * 4 + reg) * 8 + (key & 7)] = f2bf(s[nt][reg]);
        }

      // O += P V
      __builtin_amdgcn_s_setprio(1);
#pragma unroll
      for (int ch2 = 0; ch2 < 2; ++ch2) {
        const int c = ch2 * 4 + quad;
        const bf16x8 pa = *(const bf16x8*)&Pw[c * 128 + l15 * 8];
#pragma unroll
        for (int nt = 0; nt < 8; ++nt) {
          const int d = nt * 16 + l15;
          const bf16x8 vv = *(const bf16x8*)&Vs[buf][d * 64 + ((c ^ l7) << 3)];
          o[nt] = mfma16(pa, vv, o[nt]);
        }
      }
      __builtin_amdgcn_s_setprio(0);

      // single barrier per iter: next tile's loads (issued at top) now land.
      asm volatile("s_waitcnt vmcnt(0)\n\ts_barrier" ::: "memory");
      buf ^= 1;
    }

    // epilogue: normalize and store attn output as (B*S, D) bf16
#pragma unroll
    for (int reg = 0; reg < 4; ++reg) {
      const int sq = qt * 64 + w * 16 + quad * 4 + reg;
      const float inv_l = 1.0f / lrow[reg];
      unsigned short* ob = Oa + (size_t)(b * SEQ + sq) * DMODEL + h * HD;
#pragma unroll
      for (int nt = 0; nt < 8; ++nt) ob[nt * 16 + l15] = f2bf(o[nt][reg] * inv_l);
    }
  }
}

extern "C" void kernel_launch(void* const* d_in, const int* in_sizes, int n_in,
                              void* d_out, int out_size, void* d_ws, size_t ws_size,
                              hipStream_t stream) {
  const float* x = (const float*)d_in[0];
  const float* Wq = (const float*)d_in[1];
  const float* Wk = (const float*)d_in[2];
  const float* Wv = (const float*)d_in[3];
  const float* Wo = (const float*)d_in[4];
  float* out = (float*)d_out;

  const size_t NX = (size_t)2 * SEQ * DMODEL;
  const size_t NW = (size_t)DMODEL * DMODEL;
  unsigned short* ws = (unsigned short*)d_ws;
  unsigned short* xb = ws;
  unsigned short* wqb = xb + NX;   // wq/wk/wv contiguous -> fused N=6144 B operand
  unsigned short* wkb = wqb + NW;
  unsigned short* wvb = wkb + NW;
  unsigned short* wob = wvb + NW;
  unsigned short* qb = wob + NW;  // (B,H,S,hd) permuted-hd, rope'd, *log2e/sqrt(hd)
  unsigned short* kb = qb + NX;   // (B,H,S,hd) permuted-hd, rope'd
  unsigned short* vb = kb + NX;   // (B,H,hd,S)
  unsigned short* ab = vb + NX;   // (B*S, D)
  float2* rtab = (float2*)(ab + NX);  // 2048 x 64 cos/sin (1 MB)

  cvt_all<<<25088, 256, 0, stream>>>(x, Wq, Wk, Wv, Wo, ws, rtab);
  gemm_pipe<0><<<dim3(32, 16), 512, 0, stream>>>(xb, wqb, qb, nullptr, rtab);
  attn_kernel<<<512, 256, 0, stream>>>(qb, kb, vb, ab);
  gemm_pipe<1><<<dim3(16, 16), 512, 0, stream>>>(ab, wob, nullptr, out, nullptr);
}